// Round 4
// baseline (518.894 us; speedup 1.0000x reference)
//
#include <hip/hip_runtime.h>

// GridGraph adjacency (COO) for all-active 2048x2048 rook grid.
// Output layout (float32): [vals(4N) | rows(4N) | cols(4N)], direction-major
// within each: d*N + p, d in ROOK order (down, up, right, left).
//
// R9c: R9 with the compile fix — __builtin_nontemporal_store requires a
// native clang vector type, not HIP's float4 class. Use
// ext_vector_type(4) float (same 16B layout/alignment -> still one
// global_store_dwordx4, now with the nt policy bit).
// Theory unchanged: plain global stores ALLOCATE in L2; streaming 201MB of
// never-re-read output through 4MiB/XCD L2 serializes behind dirty
// evictions. The harness fill (6.7 TB/s on the same buffer) bypasses
// cache. Each lane owns one full 64B line (4 consecutive float4s) so every
// store is whole-line. Keep R8's stream-per-block layout (neutral, clean).

constexpr int HH = 2048;
constexpr int WW = 2048;
constexpr int NN = HH * WW;            // 4,194,304 — fits in int

typedef float f32x4 __attribute__((ext_vector_type(4)));

__global__ __launch_bounds__(1024) void grid_adj_nt(
    const float* __restrict__ w, float* __restrict__ out)
{
    // blockIdx.x = s*256 + blk : s = stream (a*4+d), blk = chunk within stream
    const int s   = blockIdx.x >> 8;    // 0..11
    const int blk = blockIdx.x & 255;
    const int d   = s & 3;              // 0=down 1=up 2=right 3=left

    float* __restrict__ dst = out + (long long)s * NN;

    // Each lane owns 16 consecutive floats (one 64B line):
    // chunk = 16384 floats (64 KiB) per block; lane base = blk*16384 + tid*16.
    const int base = (blk << 14) + ((int)threadIdx.x << 4);

#pragma unroll
    for (int it = 0; it < 4; ++it) {
        const int p = base + (it << 2);
        const int j = p & (WW - 1);     // column of first of the 4 elems
        const float fp = (float)p;
        f32x4 r = (f32x4){0.f, 0.f, 0.f, 0.f};

        if (d == 0) {                   // down (i+1, j): valid iff p < NN-WW
            if (p < NN - WW) {
                if (s == 0)      r = *(const f32x4*)(w + p + WW);
                else if (s == 4) r = (f32x4){fp, fp + 1.f, fp + 2.f, fp + 3.f};
                else {           const float fq = fp + (float)WW;
                                 r = (f32x4){fq, fq + 1.f, fq + 2.f, fq + 3.f}; }
            }
        } else if (d == 1) {            // up (i-1, j): valid iff p >= WW
            if (p >= WW) {
                if (s == 1)      r = *(const f32x4*)(w + p - WW);
                else if (s == 5) r = (f32x4){fp, fp + 1.f, fp + 2.f, fp + 3.f};
                else {           const float fq = fp - (float)WW;
                                 r = (f32x4){fq, fq + 1.f, fq + 2.f, fq + 3.f}; }
            }
        } else if (d == 2) {            // right (i, j+1): only k=3 at j==WW-4 invalid
            const bool lastok = (j < WW - 4);
            if (s == 2) {
                const f32x4 c0 = *(const f32x4*)(w + p);
                float w4 = 0.f;
                if (lastok) w4 = w[p + 4];          // guards OOB read at p+4==NN
                r = (f32x4){c0.y, c0.z, c0.w, w4};
            } else if (s == 6) {
                r = (f32x4){fp, fp + 1.f, fp + 2.f, lastok ? fp + 3.f : 0.f};
            } else {
                r = (f32x4){fp + 1.f, fp + 2.f, fp + 3.f, lastok ? fp + 4.f : 0.f};
            }
        } else {                        // left (i, j-1): only k=0 at j==0 invalid
            const bool firstok = (j > 0);
            if (s == 3) {
                const f32x4 c0 = *(const f32x4*)(w + p);
                float wm1 = 0.f;
                if (firstok) wm1 = w[p - 1];        // guards OOB read at p==0
                r = (f32x4){wm1, c0.x, c0.y, c0.z};
            } else if (s == 7) {
                r = (f32x4){firstok ? fp : 0.f, fp + 1.f, fp + 2.f, fp + 3.f};
            } else {
                r = (f32x4){firstok ? fp - 1.f : 0.f, fp, fp + 1.f, fp + 2.f};
            }
        }

        __builtin_nontemporal_store(r, (f32x4*)(dst + p));
    }
}

extern "C" void kernel_launch(void* const* d_in, const int* in_sizes, int n_in,
                              void* d_out, int out_size, void* d_ws, size_t ws_size,
                              hipStream_t stream) {
    // d_in[0] = activities (all-true bool, unused), d_in[1] = vertex_weights f32 [H*W]
    const float* w = (const float*)d_in[1];
    float* out = (float*)d_out;

    const int threads = 1024;
    const int blocks  = 12 * 256;       // 12 streams x 256 chunks (64 KiB each)
    grid_adj_nt<<<blocks, threads, 0, stream>>>(w, out);
}

// Round 5
// 219.515 us; speedup vs baseline: 2.3638x; 2.3638x over previous
//
#include <hip/hip_runtime.h>

// GridGraph adjacency (COO) for all-active 2048x2048 rook grid.
// Output layout (float32): [vals(4N) | rows(4N) | cols(4N)], direction-major
// within each: d*N + p, d in ROOK order (down, up, right, left).
//
// R10: nt stores, DECONFOUNDED. R9c regressed 4x (kernel 360us, WRITE_SIZE
// 2.08x logical, FETCH 3x) because lane-owns-a-line addressing made each
// store instruction touch 64 different lines with 16B each; with nt
// bypassing L2's write combining, every fragment became a partial-line HBM
// RMW. Fix: back to R8 wave-coalesced addressing (each store instruction
// = 64 lanes x 16B = 1KiB contiguous = 16 FULL lines) and keep the nt
// policy. This is the clean test of "L2 allocation costs us" — if neutral
// or worse, revert to plain R8 and declare roofline.

constexpr int HH = 2048;
constexpr int WW = 2048;
constexpr int NN = HH * WW;            // 4,194,304 — fits in int

typedef float f32x4 __attribute__((ext_vector_type(4)));

__global__ __launch_bounds__(1024) void grid_adj_nt2(
    const float* __restrict__ w, float* __restrict__ out)
{
    // blockIdx.x = s*256 + blk : s = stream (a*4+d), blk = chunk within stream
    const int s   = blockIdx.x >> 8;    // 0..11
    const int blk = blockIdx.x & 255;
    const int d   = s & 3;              // 0=down 1=up 2=right 3=left

    float* __restrict__ dst = out + (long long)s * NN;

    // R8 addressing: 4 iterations x 1024 threads x float4, wave-coalesced;
    // block covers 64 KiB contiguous per stream.
#pragma unroll
    for (int it = 0; it < 4; ++it) {
        const int p = ((blk << 2) + it) * 4096 + ((int)threadIdx.x << 2);
        const int j = p & (WW - 1);     // column of first of the 4 elems
        const float fp = (float)p;
        f32x4 r = (f32x4){0.f, 0.f, 0.f, 0.f};

        if (d == 0) {                   // down (i+1, j): valid iff p < NN-WW
            if (p < NN - WW) {
                if (s == 0)      r = *(const f32x4*)(w + p + WW);
                else if (s == 4) r = (f32x4){fp, fp + 1.f, fp + 2.f, fp + 3.f};
                else {           const float fq = fp + (float)WW;
                                 r = (f32x4){fq, fq + 1.f, fq + 2.f, fq + 3.f}; }
            }
        } else if (d == 1) {            // up (i-1, j): valid iff p >= WW
            if (p >= WW) {
                if (s == 1)      r = *(const f32x4*)(w + p - WW);
                else if (s == 5) r = (f32x4){fp, fp + 1.f, fp + 2.f, fp + 3.f};
                else {           const float fq = fp - (float)WW;
                                 r = (f32x4){fq, fq + 1.f, fq + 2.f, fq + 3.f}; }
            }
        } else if (d == 2) {            // right (i, j+1): only k=3 at j==WW-4 invalid
            const bool lastok = (j < WW - 4);
            if (s == 2) {
                const f32x4 c0 = *(const f32x4*)(w + p);
                float w4 = 0.f;
                if (lastok) w4 = w[p + 4];          // guards OOB read at p+4==NN
                r = (f32x4){c0.y, c0.z, c0.w, w4};
            } else if (s == 6) {
                r = (f32x4){fp, fp + 1.f, fp + 2.f, lastok ? fp + 3.f : 0.f};
            } else {
                r = (f32x4){fp + 1.f, fp + 2.f, fp + 3.f, lastok ? fp + 4.f : 0.f};
            }
        } else {                        // left (i, j-1): only k=0 at j==0 invalid
            const bool firstok = (j > 0);
            if (s == 3) {
                const f32x4 c0 = *(const f32x4*)(w + p);
                float wm1 = 0.f;
                if (firstok) wm1 = w[p - 1];        // guards OOB read at p==0
                r = (f32x4){wm1, c0.x, c0.y, c0.z};
            } else if (s == 7) {
                r = (f32x4){firstok ? fp : 0.f, fp + 1.f, fp + 2.f, fp + 3.f};
            } else {
                r = (f32x4){firstok ? fp - 1.f : 0.f, fp, fp + 1.f, fp + 2.f};
            }
        }

        __builtin_nontemporal_store(r, (f32x4*)(dst + p));
    }
}

extern "C" void kernel_launch(void* const* d_in, const int* in_sizes, int n_in,
                              void* d_out, int out_size, void* d_ws, size_t ws_size,
                              hipStream_t stream) {
    // d_in[0] = activities (all-true bool, unused), d_in[1] = vertex_weights f32 [H*W]
    const float* w = (const float*)d_in[1];
    float* out = (float*)d_out;

    const int threads = 1024;
    const int blocks  = 12 * 256;       // 12 streams x 256 chunks (64 KiB each)
    grid_adj_nt2<<<blocks, threads, 0, stream>>>(w, out);
}

// Round 6
// 211.886 us; speedup vs baseline: 2.4489x; 1.0360x over previous
//
#include <hip/hip_runtime.h>

// GridGraph adjacency (COO) for all-active 2048x2048 rook grid.
// Output layout (float32): [vals(4N) | rows(4N) | cols(4N)], direction-major
// within each: d*N + p, d in ROOK order (down, up, right, left).
//
// R11: FINAL — revert to R8's plain-store body (best measured: 212.1us).
// Session ledger:
//   R7  interleaved 12-stream/thread, plain stores ... 213.0
//   R8  stream-per-block, plain stores ............... 212.1  <- best
//   R9c nt + lane-owns-line .......................... 518.9  (partial-line
//       RMW: WRITE_SIZE 2.08x, FETCH 3x — nt defeats write combining)
//   R10 nt + wave-coalesced .......................... 219.5  (nt null/neg)
// Decomposition (calibrated via R9c's visible dispatch): total 212 =
// harness poison fill ~120us (805MB @6.6TB/s, fixed) + ~39us reset/launch
// overhead (fixed) + kernel ~53us (201MB write + 17MB L3-resident read,
// ~4.1 TB/s; ideal ~33us). Remaining knob <=20us; write topology, launch
// shape, and cache policy all measured null -> at the practical roofline.

constexpr int HH = 2048;
constexpr int WW = 2048;
constexpr int NN = HH * WW;            // 4,194,304 — fits in int

typedef float f32x4 __attribute__((ext_vector_type(4)));

__global__ __launch_bounds__(1024) void grid_adj_stream(
    const float* __restrict__ w, float* __restrict__ out)
{
    // blockIdx.x = s*256 + blk : s = stream (a*4+d), blk = chunk within stream
    const int s   = blockIdx.x >> 8;    // 0..11
    const int blk = blockIdx.x & 255;
    const int d   = s & 3;              // 0=down 1=up 2=right 3=left

    float* __restrict__ dst = out + (long long)s * NN;

    // 4 iterations x 1024 threads x float4 = 16384 elems = 64 KiB contiguous
#pragma unroll
    for (int it = 0; it < 4; ++it) {
        const int p = ((blk << 2) + it) * 4096 + ((int)threadIdx.x << 2);
        const int j = p & (WW - 1);     // column of first of the 4 elems
        const float fp = (float)p;
        f32x4 r = (f32x4){0.f, 0.f, 0.f, 0.f};

        if (d == 0) {                   // down (i+1, j): valid iff p < NN-WW
            if (p < NN - WW) {
                if (s == 0)      r = *(const f32x4*)(w + p + WW);
                else if (s == 4) r = (f32x4){fp, fp + 1.f, fp + 2.f, fp + 3.f};
                else {           const float fq = fp + (float)WW;
                                 r = (f32x4){fq, fq + 1.f, fq + 2.f, fq + 3.f}; }
            }
        } else if (d == 1) {            // up (i-1, j): valid iff p >= WW
            if (p >= WW) {
                if (s == 1)      r = *(const f32x4*)(w + p - WW);
                else if (s == 5) r = (f32x4){fp, fp + 1.f, fp + 2.f, fp + 3.f};
                else {           const float fq = fp - (float)WW;
                                 r = (f32x4){fq, fq + 1.f, fq + 2.f, fq + 3.f}; }
            }
        } else if (d == 2) {            // right (i, j+1): only k=3 at j==WW-4 invalid
            const bool lastok = (j < WW - 4);
            if (s == 2) {
                const f32x4 c0 = *(const f32x4*)(w + p);
                float w4 = 0.f;
                if (lastok) w4 = w[p + 4];          // guards OOB read at p+4==NN
                r = (f32x4){c0.y, c0.z, c0.w, w4};
            } else if (s == 6) {
                r = (f32x4){fp, fp + 1.f, fp + 2.f, lastok ? fp + 3.f : 0.f};
            } else {
                r = (f32x4){fp + 1.f, fp + 2.f, fp + 3.f, lastok ? fp + 4.f : 0.f};
            }
        } else {                        // left (i, j-1): only k=0 at j==0 invalid
            const bool firstok = (j > 0);
            if (s == 3) {
                const f32x4 c0 = *(const f32x4*)(w + p);
                float wm1 = 0.f;
                if (firstok) wm1 = w[p - 1];        // guards OOB read at p==0
                r = (f32x4){wm1, c0.x, c0.y, c0.z};
            } else if (s == 7) {
                r = (f32x4){firstok ? fp : 0.f, fp + 1.f, fp + 2.f, fp + 3.f};
            } else {
                r = (f32x4){firstok ? fp - 1.f : 0.f, fp, fp + 1.f, fp + 2.f};
            }
        }

        *(f32x4*)(dst + p) = r;
    }
}

extern "C" void kernel_launch(void* const* d_in, const int* in_sizes, int n_in,
                              void* d_out, int out_size, void* d_ws, size_t ws_size,
                              hipStream_t stream) {
    // d_in[0] = activities (all-true bool, unused), d_in[1] = vertex_weights f32 [H*W]
    const float* w = (const float*)d_in[1];
    float* out = (float*)d_out;

    const int threads = 1024;
    const int blocks  = 12 * 256;       // 12 streams x 256 chunks (64 KiB each)
    grid_adj_stream<<<blocks, threads, 0, stream>>>(w, out);
}